// Round 1
// baseline (407.999 us; speedup 1.0000x reference)
//
#include <hip/hip_runtime.h>

// ---------------------------------------------------------------------------
// Fused GQA attention block for MI355X (gfx950), bf16 MFMA pipeline.
// B=1, S=4096, H=2048, NH=16, NKV=4, HD=128, GROUPS=4, causal mask hardcoded.
// ---------------------------------------------------------------------------

typedef __bf16 bf16;
typedef float f32x4 __attribute__((ext_vector_type(4)));
typedef bf16 bf16x4 __attribute__((ext_vector_type(4)));
typedef bf16 bf16x8 __attribute__((ext_vector_type(8)));

#define MFMA16(A, B, C) __builtin_amdgcn_mfma_f32_16x16x32_bf16((A), (B), (C), 0, 0, 0)

// async global->LDS, 16B per lane. LDS dest must be wave-uniform; HW writes
// lane i at ldsbase + i*16.
__device__ __forceinline__ void async16(const bf16* g, bf16* l) {
  __builtin_amdgcn_global_load_lds(
      (const __attribute__((address_space(1))) unsigned int*)g,
      (__attribute__((address_space(3))) unsigned int*)l, 16, 0, 0);
}

// ---------------------------------------------------------------------------
// f32 -> bf16 elementwise cast (vectorized float4 -> bf16x4)
// ---------------------------------------------------------------------------
__global__ void cast_bf16_kernel(const float* __restrict__ in,
                                 bf16* __restrict__ out, int n4) {
  int i = blockIdx.x * blockDim.x + threadIdx.x;
  int stride = gridDim.x * blockDim.x;
  for (; i < n4; i += stride) {
    float4 v = ((const float4*)in)[i];
    bf16x4 o = {(bf16)v.x, (bf16)v.y, (bf16)v.z, (bf16)v.w};
    ((bf16x4*)out)[i] = o;
  }
}

// ---------------------------------------------------------------------------
// Transpose + cast: src f32 [2048 rows(K)][srcCols], dst bf16 [srcCols][2048].
// scale folded in (used to fold 1/sqrt(HD) into Wq^T).
// ---------------------------------------------------------------------------
__global__ void transpose_cast_kernel(const float* __restrict__ src, int srcCols,
                                      bf16* __restrict__ dst, float scale) {
  __shared__ float t[64][65];  // +1 pad: conflict-free transpose
  const int kt = blockIdx.y * 64;
  const int nt = blockIdx.x * 64;
  const int r0 = threadIdx.x >> 4;
  const int c0 = (threadIdx.x & 15) * 4;
#pragma unroll
  for (int i = 0; i < 4; ++i) {
    int r = r0 + i * 16;
    float4 v = *(const float4*)(src + (kt + r) * srcCols + nt + c0);
    t[r][c0 + 0] = v.x; t[r][c0 + 1] = v.y; t[r][c0 + 2] = v.z; t[r][c0 + 3] = v.w;
  }
  __syncthreads();
#pragma unroll
  for (int i = 0; i < 4; ++i) {
    int r = r0 + i * 16;
    bf16x4 b = {(bf16)(t[c0 + 0][r] * scale), (bf16)(t[c0 + 1][r] * scale),
                (bf16)(t[c0 + 2][r] * scale), (bf16)(t[c0 + 3][r] * scale)};
    *(bf16x4*)(dst + (nt + r) * 2048 + kt + c0) = b;
  }
}

// ---------------------------------------------------------------------------
// 128x128-tile bf16 GEMM, BK=32, 4 waves (2x2), m97-style global_load_lds.
//   A  [M][K]  row-major  (K = 2048)
//   BT [N][K]  row-major  (B transposed)
// MODE 0: QKV epilogue -> Qb [4096][2048], Kb [4096][512], Vt [512][4096] (!transposed)
// MODE 1: f32 epilogue -> Cf [4096][2048]
// grid: (N/128, M/128)
// ---------------------------------------------------------------------------
template <int MODE>
__global__ __launch_bounds__(256, 2) void gemm_bt(
    const bf16* __restrict__ A, const bf16* __restrict__ BT, int K,
    bf16* __restrict__ Qb, bf16* __restrict__ Kb, bf16* __restrict__ Vt,
    float* __restrict__ Cf) {
  __shared__ bf16 As[128 * 32];
  __shared__ bf16 Bs[128 * 32];
  const int tid = threadIdx.x;
  const int w = tid >> 6, lane = tid & 63, g = lane >> 4, lq = lane & 15;
  const int wr = w >> 1, wc = w & 1;
  const int mBase = blockIdx.y * 128, nBase = blockIdx.x * 128;

  f32x4 acc[4][4] = {};
  const int KT = K >> 5;
  for (int kt = 0; kt < KT; ++kt) {
    // stage A-tile [128][32] and B-tile [128][32] (16B chunks, linear LDS)
#pragma unroll
    for (int r = 0; r < 2; ++r) {
      int chunk = r * 256 + tid;
      int row = chunk >> 2, cu = chunk & 3;
      async16(A + (mBase + row) * K + kt * 32 + cu * 8, As + (r * 256 + w * 64) * 8);
      async16(BT + (nBase + row) * K + kt * 32 + cu * 8, Bs + (r * 256 + w * 64) * 8);
    }
    asm volatile("s_waitcnt vmcnt(0)" ::: "memory");
    __syncthreads();

    bf16x8 af[4], bfr[4];
#pragma unroll
    for (int i = 0; i < 4; ++i)
      af[i] = *(const bf16x8*)(As + (wr * 64 + i * 16 + lq) * 32 + g * 8);
#pragma unroll
    for (int i = 0; i < 4; ++i)
      bfr[i] = *(const bf16x8*)(Bs + (wc * 64 + i * 16 + lq) * 32 + g * 8);
#pragma unroll
    for (int mi = 0; mi < 4; ++mi)
#pragma unroll
      for (int ni = 0; ni < 4; ++ni)
        acc[mi][ni] = MFMA16(af[mi], bfr[ni], acc[mi][ni]);
    __syncthreads();
  }

  // epilogue: C row = (lane>>4)*4 + jr, col = lane&15  (m89-verified layout)
#pragma unroll
  for (int mi = 0; mi < 4; ++mi)
#pragma unroll
    for (int ni = 0; ni < 4; ++ni) {
      const int n = nBase + wc * 64 + ni * 16 + lq;
      const int m0 = mBase + wr * 64 + mi * 16 + 4 * g;
      if (MODE == 0) {
        if (nBase < 2048) {
#pragma unroll
          for (int jr = 0; jr < 4; ++jr)
            Qb[(m0 + jr) * 2048 + n] = (bf16)acc[mi][ni][jr];
        } else if (nBase < 2560) {
#pragma unroll
          for (int jr = 0; jr < 4; ++jr)
            Kb[(m0 + jr) * 512 + (n - 2048)] = (bf16)acc[mi][ni][jr];
        } else {
          // V written transposed: Vt[n-2560][m], 4 consecutive m -> 8B store
          bf16x4 v = {(bf16)acc[mi][ni][0], (bf16)acc[mi][ni][1],
                      (bf16)acc[mi][ni][2], (bf16)acc[mi][ni][3]};
          *(bf16x4*)(Vt + (n - 2560) * 4096 + m0) = v;
        }
      } else {
#pragma unroll
        for (int jr = 0; jr < 4; ++jr)
          Cf[(m0 + jr) * 2048 + n] = acc[mi][ni][jr];
      }
    }
}

// ---------------------------------------------------------------------------
// Causal flash attention, GQA (kv = h>>2). One block = (head, q-tile of 128).
// 4 waves x 32 q-rows. K/Vt tiles staged in LDS with XOR swizzle
// (byte ^= (row&7)<<4 within 256B rows; inverse swizzle applied to the GLOBAL
// source so global_load_lds keeps a linear LDS dest — rule #21).
// P does an LDS round-trip through the (dead) K region, per-wave private.
// ---------------------------------------------------------------------------
__global__ __launch_bounds__(256, 2) void attn_fwd(
    const bf16* __restrict__ Qb,  // [4096][2048], pre-scaled by 1/sqrt(128)
    const bf16* __restrict__ Kb,  // [4096][512]
    const bf16* __restrict__ Vt,  // [512][4096]
    bf16* __restrict__ AO) {      // [4096][2048]
  __shared__ bf16 Ks[128 * 128];  // 32KB; reused as P after S-phase
  __shared__ bf16 Vs[128 * 128];  // 32KB, layout Vs[d][key]

  const int bid = blockIdx.x;
  const int h = bid & 15;
  // heavy/light pairing: bid and bid+256 land on the same CU (round-robin),
  // (qt+1) + (32-qt) = 33 tiles per CU -> balanced causal work.
  const int qt = (bid < 256) ? (bid >> 4) : (31 - ((bid - 256) >> 4));
  const int kv = h >> 2;
  const int tid = threadIdx.x;
  const int w = tid >> 6, lane = tid & 63, g = lane >> 4, lq = lane & 15;
  const int sx = (lq & 7) << 4;  // read-side XOR (row&7 == lq&7 for all frag reads)
  bf16* Ps = Ks + w * 4096;      // per-wave 32x128 P tile (8KB)

  // Q fragments in registers: rows = qt*128 + w*32 + mi*16 + lq
  bf16x8 aq[2][4];
#pragma unroll
  for (int mi = 0; mi < 2; ++mi)
#pragma unroll
    for (int kk = 0; kk < 4; ++kk)
      aq[mi][kk] = *(const bf16x8*)(Qb + (qt * 128 + w * 32 + mi * 16 + lq) * 2048 +
                                    h * 128 + kk * 32 + g * 8);

  float mstate[2][4], lstate[2][4];
  f32x4 o[2][8] = {};
#pragma unroll
  for (int mi = 0; mi < 2; ++mi)
#pragma unroll
    for (int jr = 0; jr < 4; ++jr) { mstate[mi][jr] = -1e30f; lstate[mi][jr] = 0.f; }

  for (int kt = 0; kt <= qt; ++kt) {
    // ---- stage K tile [128 key][128 d] and Vt tile [128 d][128 key] ----
#pragma unroll
    for (int r = 0; r < 8; ++r) {
      int chunk = r * 256 + tid;
      int row = chunk >> 4, cu = chunk & 15;
      int sc = (cu ^ (row & 7)) * 8;  // inverse-swizzled global source
      async16(Kb + (kt * 128 + row) * 512 + kv * 128 + sc, Ks + (r * 256 + w * 64) * 8);
      async16(Vt + (kv * 128 + row) * 4096 + kt * 128 + sc, Vs + (r * 256 + w * 64) * 8);
    }
    asm volatile("s_waitcnt vmcnt(0)" ::: "memory");
    __syncthreads();

    // ---- S = Q @ K^T  (per wave: 32 q-rows x 128 keys) ----
    f32x4 s[2][8] = {};
#pragma unroll
    for (int ni = 0; ni < 8; ++ni) {
      const int krow = ni * 16 + lq;  // key index
#pragma unroll
      for (int kk = 0; kk < 4; ++kk) {
        bf16x8 bk = *(const bf16x8*)((const char*)Ks + krow * 256 + ((kk * 64 + g * 16) ^ sx));
        s[0][ni] = MFMA16(aq[0][kk], bk, s[0][ni]);
        s[1][ni] = MFMA16(aq[1][kk], bk, s[1][ni]);
      }
    }

    // ---- causal mask on the diagonal tile ----
    if (kt == qt) {
#pragma unroll
      for (int mi = 0; mi < 2; ++mi)
#pragma unroll
        for (int ni = 0; ni < 8; ++ni)
#pragma unroll
          for (int jr = 0; jr < 4; ++jr) {
            int key = ni * 16 + lq;
            int q = w * 32 + mi * 16 + 4 * g + jr;
            if (key > q) s[mi][ni][jr] = -1e30f;
          }
    }
    __syncthreads();  // all waves done reading Ks -> safe to overwrite with P

    // ---- online softmax ----
    float mnew[2][4], al[2][4];
#pragma unroll
    for (int mi = 0; mi < 2; ++mi)
#pragma unroll
      for (int jr = 0; jr < 4; ++jr) {
        float pm = s[mi][0][jr];
#pragma unroll
        for (int ni = 1; ni < 8; ++ni) pm = fmaxf(pm, s[mi][ni][jr]);
        pm = fmaxf(pm, __shfl_xor(pm, 1));
        pm = fmaxf(pm, __shfl_xor(pm, 2));
        pm = fmaxf(pm, __shfl_xor(pm, 4));
        pm = fmaxf(pm, __shfl_xor(pm, 8));
        float mo = mstate[mi][jr];
        float mn = fmaxf(mo, pm);
        mnew[mi][jr] = mn;
        al[mi][jr] = __expf(mo - mn);
        mstate[mi][jr] = mn;
      }

    // P = exp(S - m), write to swizzled P-LDS, accumulate row sums
    float rs[2][4] = {};
#pragma unroll
    for (int mi = 0; mi < 2; ++mi)
#pragma unroll
      for (int ni = 0; ni < 8; ++ni)
#pragma unroll
        for (int jr = 0; jr < 4; ++jr) {
          float p = __expf(s[mi][ni][jr] - mnew[mi][jr]);
          rs[mi][jr] += p;
          int q = mi * 16 + 4 * g + jr;
          int k2 = (ni * 16 + lq) * 2;
          *(bf16*)((char*)Ps + q * 256 + (k2 ^ ((q & 7) << 4))) = (bf16)p;
        }
#pragma unroll
    for (int mi = 0; mi < 2; ++mi)
#pragma unroll
      for (int jr = 0; jr < 4; ++jr) {
        float r2 = rs[mi][jr];
        r2 += __shfl_xor(r2, 1);
        r2 += __shfl_xor(r2, 2);
        r2 += __shfl_xor(r2, 4);
        r2 += __shfl_xor(r2, 8);
        lstate[mi][jr] = lstate[mi][jr] * al[mi][jr] + r2;
      }
    // rescale O
#pragma unroll
    for (int mi = 0; mi < 2; ++mi)
#pragma unroll
      for (int ni = 0; ni < 8; ++ni)
#pragma unroll
        for (int jr = 0; jr < 4; ++jr) o[mi][ni][jr] *= al[mi][jr];

    asm volatile("s_waitcnt lgkmcnt(0)" ::: "memory");  // P writes visible wave-wide

    // ---- O += P @ V ----
#pragma unroll
    for (int kk = 0; kk < 4; ++kk) {
      bf16x8 pa0 = *(const bf16x8*)((const char*)Ps + (lq) * 256 + ((kk * 64 + g * 16) ^ sx));
      bf16x8 pa1 = *(const bf16x8*)((const char*)Ps + (16 + lq) * 256 + ((kk * 64 + g * 16) ^ sx));
#pragma unroll
      for (int ni = 0; ni < 8; ++ni) {
        const int d = ni * 16 + lq;
        bf16x8 bv = *(const bf16x8*)((const char*)Vs + d * 256 + ((kk * 64 + g * 16) ^ sx));
        o[0][ni] = MFMA16(pa0, bv, o[0][ni]);
        o[1][ni] = MFMA16(pa1, bv, o[1][ni]);
      }
    }
    __syncthreads();  // PV reads done before next stage overwrites Ks/Vs
  }

  // ---- epilogue: normalize and store ----
#pragma unroll
  for (int mi = 0; mi < 2; ++mi) {
    float inv[4];
#pragma unroll
    for (int jr = 0; jr < 4; ++jr) inv[jr] = 1.0f / lstate[mi][jr];
#pragma unroll
    for (int ni = 0; ni < 8; ++ni)
#pragma unroll
      for (int jr = 0; jr < 4; ++jr) {
        int row = qt * 128 + w * 32 + mi * 16 + 4 * g + jr;
        int col = h * 128 + ni * 16 + lq;
        AO[row * 2048 + col] = (bf16)(o[mi][ni][jr] * inv[jr]);
      }
  }
}

// ---------------------------------------------------------------------------
// Launch. Workspace layout (peak 54.6MB, sequential reuse):
//   [0        , 16777216) : Xb  (X in bf16)      -> reused as AO after QKV GEMM
//   [16777216 , 29360128) : WT  (Wq|Wk|Wv)^T bf16 -> reused as Wo^T after QKV GEMM
//   [29360128 , 46137344) : Qb  [4096][2048] bf16 (pre-scaled by 1/sqrt(128))
//   [46137344 , 50331648) : Kb  [4096][512]  bf16
//   [50331648 , 54525952) : Vt  [512][4096]  bf16 (V transposed)
// ---------------------------------------------------------------------------
extern "C" void kernel_launch(void* const* d_in, const int* in_sizes, int n_in,
                              void* d_out, int out_size, void* d_ws, size_t ws_size,
                              hipStream_t stream) {
  const float* X = (const float*)d_in[0];
  // d_in[1] = attention_mask: exact causal -> hardcoded in attn_fwd
  const float* Wq = (const float*)d_in[2];
  const float* Wk = (const float*)d_in[3];
  const float* Wv = (const float*)d_in[4];
  const float* Wo = (const float*)d_in[5];
  float* out = (float*)d_out;
  char* ws = (char*)d_ws;

  bf16* Xb = (bf16*)ws;
  bf16* WT = (bf16*)(ws + 16777216);
  bf16* Qb = (bf16*)(ws + 29360128);
  bf16* Kb = (bf16*)(ws + 46137344);
  bf16* Vt = (bf16*)(ws + 50331648);

  cast_bf16_kernel<<<2048, 256, 0, stream>>>(X, Xb, (4096 * 2048) / 4);
  transpose_cast_kernel<<<dim3(32, 32), 256, 0, stream>>>(Wq, 2048, WT, 0.08838834764831845f);
  transpose_cast_kernel<<<dim3(8, 32), 256, 0, stream>>>(Wk, 512, WT + 2048 * 2048, 1.0f);
  transpose_cast_kernel<<<dim3(8, 32), 256, 0, stream>>>(Wv, 512, WT + 2560 * 2048, 1.0f);

  gemm_bt<0><<<dim3(24, 32), 256, 0, stream>>>(Xb, WT, 2048, Qb, Kb, Vt, (float*)nullptr);

  // WT region now dead -> Wo^T
  transpose_cast_kernel<<<dim3(32, 32), 256, 0, stream>>>(Wo, 2048, WT, 1.0f);

  // Xb region now dead -> AO
  attn_fwd<<<512, 256, 0, stream>>>(Qb, Kb, Vt, Xb);

  gemm_bt<1><<<dim3(16, 32), 256, 0, stream>>>(Xb, WT, 2048, (bf16*)nullptr,
                                               (bf16*)nullptr, (bf16*)nullptr, out);
}

// Round 2
// 281.500 us; speedup vs baseline: 1.4494x; 1.4494x over previous
//
#include <hip/hip_runtime.h>

// ---------------------------------------------------------------------------
// Fused GQA attention block for MI355X (gfx950), bf16 MFMA pipeline.
// B=1, S=4096, H=2048, NH=16, NKV=4, HD=128, GROUPS=4, causal mask hardcoded.
// Round 2: swapped-QK^T attention (P in registers), KVBLK=64 double-buffered
// staging with counted vmcnt, exp2-domain softmax with defer-max.
// ---------------------------------------------------------------------------

typedef __bf16 bf16;
typedef float f32x4 __attribute__((ext_vector_type(4)));
typedef bf16 bf16x4 __attribute__((ext_vector_type(4)));
typedef bf16 bf16x8 __attribute__((ext_vector_type(8)));

#define MFMA16(A, B, C) __builtin_amdgcn_mfma_f32_16x16x32_bf16((A), (B), (C), 0, 0, 0)

__device__ __forceinline__ void async16(const bf16* g, bf16* l) {
  __builtin_amdgcn_global_load_lds(
      (const __attribute__((address_space(1))) unsigned int*)g,
      (__attribute__((address_space(3))) unsigned int*)l, 16, 0, 0);
}

__device__ __forceinline__ float exp2v(float x) {  // 2^x via v_exp_f32
  float r; asm("v_exp_f32 %0, %1" : "=v"(r) : "v"(x)); return r;
}
__device__ __forceinline__ unsigned cvtpk(float a, float b) {  // lo=a, hi=b
  unsigned r; asm("v_cvt_pk_bf16_f32 %0, %1, %2" : "=v"(r) : "v"(a), "v"(b)); return r;
}

// ---------------------------------------------------------------------------
// f32 -> bf16 elementwise cast
// ---------------------------------------------------------------------------
__global__ void cast_bf16_kernel(const float* __restrict__ in,
                                 bf16* __restrict__ out, int n4) {
  int i = blockIdx.x * blockDim.x + threadIdx.x;
  int stride = gridDim.x * blockDim.x;
  for (; i < n4; i += stride) {
    float4 v = ((const float4*)in)[i];
    bf16x4 o = {(bf16)v.x, (bf16)v.y, (bf16)v.z, (bf16)v.w};
    ((bf16x4*)out)[i] = o;
  }
}

// ---------------------------------------------------------------------------
// Transpose + cast: src f32 [2048][srcCols] -> dst bf16 [srcCols][2048], *scale
// ---------------------------------------------------------------------------
__global__ void transpose_cast_kernel(const float* __restrict__ src, int srcCols,
                                      bf16* __restrict__ dst, float scale) {
  __shared__ float t[64][65];
  const int kt = blockIdx.y * 64;
  const int nt = blockIdx.x * 64;
  const int r0 = threadIdx.x >> 4;
  const int c0 = (threadIdx.x & 15) * 4;
#pragma unroll
  for (int i = 0; i < 4; ++i) {
    int r = r0 + i * 16;
    float4 v = *(const float4*)(src + (kt + r) * srcCols + nt + c0);
    t[r][c0 + 0] = v.x; t[r][c0 + 1] = v.y; t[r][c0 + 2] = v.z; t[r][c0 + 3] = v.w;
  }
  __syncthreads();
#pragma unroll
  for (int i = 0; i < 4; ++i) {
    int r = r0 + i * 16;
    bf16x4 b = {(bf16)(t[c0 + 0][r] * scale), (bf16)(t[c0 + 1][r] * scale),
                (bf16)(t[c0 + 2][r] * scale), (bf16)(t[c0 + 3][r] * scale)};
    *(bf16x4*)(dst + (nt + r) * 2048 + kt + c0) = b;
  }
}

// ---------------------------------------------------------------------------
// 128x128-tile bf16 GEMM, BK=32, 4 waves, global_load_lds staging (unchanged).
// ---------------------------------------------------------------------------
template <int MODE>
__global__ __launch_bounds__(256, 2) void gemm_bt(
    const bf16* __restrict__ A, const bf16* __restrict__ BT, int K,
    bf16* __restrict__ Qb, bf16* __restrict__ Kb, bf16* __restrict__ Vt,
    float* __restrict__ Cf) {
  __shared__ bf16 As[128 * 32];
  __shared__ bf16 Bs[128 * 32];
  const int tid = threadIdx.x;
  const int w = tid >> 6, lane = tid & 63, g = lane >> 4, lq = lane & 15;
  const int wr = w >> 1, wc = w & 1;
  const int mBase = blockIdx.y * 128, nBase = blockIdx.x * 128;

  f32x4 acc[4][4] = {};
  const int KT = K >> 5;
  for (int kt = 0; kt < KT; ++kt) {
#pragma unroll
    for (int r = 0; r < 2; ++r) {
      int chunk = r * 256 + tid;
      int row = chunk >> 2, cu = chunk & 3;
      async16(A + (mBase + row) * K + kt * 32 + cu * 8, As + (r * 256 + w * 64) * 8);
      async16(BT + (nBase + row) * K + kt * 32 + cu * 8, Bs + (r * 256 + w * 64) * 8);
    }
    asm volatile("s_waitcnt vmcnt(0)" ::: "memory");
    __syncthreads();

    bf16x8 af[4], bfr[4];
#pragma unroll
    for (int i = 0; i < 4; ++i)
      af[i] = *(const bf16x8*)(As + (wr * 64 + i * 16 + lq) * 32 + g * 8);
#pragma unroll
    for (int i = 0; i < 4; ++i)
      bfr[i] = *(const bf16x8*)(Bs + (wc * 64 + i * 16 + lq) * 32 + g * 8);
#pragma unroll
    for (int mi = 0; mi < 4; ++mi)
#pragma unroll
      for (int ni = 0; ni < 4; ++ni)
        acc[mi][ni] = MFMA16(af[mi], bfr[ni], acc[mi][ni]);
    __syncthreads();
  }

#pragma unroll
  for (int mi = 0; mi < 4; ++mi)
#pragma unroll
    for (int ni = 0; ni < 4; ++ni) {
      const int n = nBase + wc * 64 + ni * 16 + lq;
      const int m0 = mBase + wr * 64 + mi * 16 + 4 * g;
      if (MODE == 0) {
        if (nBase < 2048) {
#pragma unroll
          for (int jr = 0; jr < 4; ++jr)
            Qb[(m0 + jr) * 2048 + n] = (bf16)acc[mi][ni][jr];
        } else if (nBase < 2560) {
#pragma unroll
          for (int jr = 0; jr < 4; ++jr)
            Kb[(m0 + jr) * 512 + (n - 2048)] = (bf16)acc[mi][ni][jr];
        } else {
          bf16x4 v = {(bf16)acc[mi][ni][0], (bf16)acc[mi][ni][1],
                      (bf16)acc[mi][ni][2], (bf16)acc[mi][ni][3]};
          *(bf16x4*)(Vt + (n - 2560) * 4096 + m0) = v;
        }
      } else {
#pragma unroll
        for (int jr = 0; jr < 4; ++jr)
          Cf[(m0 + jr) * 2048 + n] = acc[mi][ni][jr];
      }
    }
}

// ---------------------------------------------------------------------------
// Causal flash attention, swapped-QK^T, P in registers.
// Block = (head, 128-row q-tile), 4 waves x 32 q-rows, KVBLK=64 double-buffered.
// Q is pre-scaled by log2e/sqrt(HD) so softmax runs in exp2 domain.
// S^T = mfma(K, Q): lane (g,lq) holds S^T[key=nt*16+4g+jr][q=lq+16*mi].
// PV: O^T = mfma(V^T, P): needs P[q=lq][key=kk2*32+8g+j] -> cvt_pk + shfl gather.
// ---------------------------------------------------------------------------
__global__ __launch_bounds__(256, 2) void attn_fwd(
    const bf16* __restrict__ Qb,  // [4096][2048], scale folded
    const bf16* __restrict__ Kb,  // [4096][512]
    const bf16* __restrict__ Vt,  // [512][4096]
    bf16* __restrict__ AO) {      // [4096][2048]
  // K: [buf][64 key][128 d], 256B rows, XOR-swizzled (byte ^= (row&7)<<4)
  // V: [buf][128 d][64 key], 128B rows, same swizzle
  __shared__ __align__(16) bf16 Ks[2][64 * 128];
  __shared__ __align__(16) bf16 Vs[2][128 * 64];

  const int bid = blockIdx.x;
  const int h = bid & 15;
  const int qt = (bid < 256) ? (bid >> 4) : (31 - ((bid - 256) >> 4));
  const int kv = h >> 2;
  const int tid = threadIdx.x;
  const int w = tid >> 6, lane = tid & 63, g = lane >> 4, lq = lane & 15;
  const int sx = (lq & 7) << 4;
  const int qbase = qt * 128;
  const int nk = 2 * (qt + 1);

  // Q fragments: Q[q = qbase + w*32 + mi*16 + lq][d = kk*32 + g*8 ..]
  bf16x8 aq[2][4];
#pragma unroll
  for (int mi = 0; mi < 2; ++mi)
#pragma unroll
    for (int kk = 0; kk < 4; ++kk)
      aq[mi][kk] = *(const bf16x8*)(Qb + (qbase + w * 32 + mi * 16 + lq) * 2048 +
                                    h * 128 + kk * 32 + g * 8);

  float mst[2] = {-1e30f, -1e30f}, lst[2] = {0.f, 0.f};
  f32x4 o[2][8] = {};  // O^T: o[mi][dt][jr] = O^T[d = dt*16+4g+jr][q(mi,lq)]

  // stage 64-key tile t into buffer t&1; inverse-swizzled global source,
  // linear LDS dest (rule #21). 8 global_load_lds per wave.
  auto STAGE = [&](int t) {
    const int b = t & 1;
#pragma unroll
    for (int r = 0; r < 4; ++r) {
      int gid = r * 256 + tid;
      int krow = gid >> 4, cu = gid & 15;
      async16(Kb + (t * 64 + krow) * 512 + kv * 128 + ((cu ^ (krow & 7)) * 8),
              &Ks[b][(r * 256 + w * 64) * 8]);
    }
#pragma unroll
    for (int r = 0; r < 4; ++r) {
      int gid = r * 256 + tid;
      int vrow = gid >> 3, gv = gid & 7;
      async16(Vt + (kv * 128 + vrow) * 4096 + t * 64 + ((gv ^ (vrow & 7)) * 8),
              &Vs[b][(r * 256 + w * 64) * 8]);
    }
  };

  STAGE(0);

  for (int t = 0; t < nk; ++t) {
    const int cur = t & 1;
    if (t + 1 < nk) {
      STAGE(t + 1);  // prefetch stays in flight across the barrier (T4)
      asm volatile("s_waitcnt vmcnt(8)" ::: "memory");
    } else {
      asm volatile("s_waitcnt vmcnt(0)" ::: "memory");
    }
    __builtin_amdgcn_s_barrier();
    __builtin_amdgcn_sched_barrier(0);

    // ---- S^T = K @ Q^T ----
    f32x4 s[2][4] = {};
#pragma unroll
    for (int nt = 0; nt < 4; ++nt)
#pragma unroll
      for (int kk = 0; kk < 4; ++kk) {
        bf16x8 bk = *(const bf16x8*)((const char*)Ks[cur] + (nt * 16 + lq) * 256 +
                                     ((kk * 64 + g * 16) ^ sx));
        s[0][nt] = MFMA16(bk, aq[0][kk], s[0][nt]);
        s[1][nt] = MFMA16(bk, aq[1][kk], s[1][nt]);
      }

    // ---- causal mask (only the last two 64-key tiles can cross the diagonal)
    if (t >= 2 * qt) {
#pragma unroll
      for (int mi = 0; mi < 2; ++mi) {
        const int q = qbase + w * 32 + mi * 16 + lq;
#pragma unroll
        for (int nt = 0; nt < 4; ++nt)
#pragma unroll
          for (int jr = 0; jr < 4; ++jr) {
            int key = t * 64 + nt * 16 + 4 * g + jr;
            if (key > q) s[mi][nt][jr] = -1e30f;
          }
      }
    }

    // ---- online softmax (exp2 domain), P packed to bf16 in registers ----
    unsigned pw[2][4][2];
#pragma unroll
    for (int mi = 0; mi < 2; ++mi) {
      float pm = s[mi][0][0];
#pragma unroll
      for (int nt = 0; nt < 4; ++nt)
#pragma unroll
        for (int jr = 0; jr < 4; ++jr) pm = fmaxf(pm, s[mi][nt][jr]);
      pm = fmaxf(pm, __shfl_xor(pm, 16));
      pm = fmaxf(pm, __shfl_xor(pm, 32));
      if (__any(pm > mst[mi] + 8.f)) {  // defer-max (T13), THR=8 in log2
        float mn = fmaxf(mst[mi], pm);
        float al = exp2v(mst[mi] - mn);
        mst[mi] = mn;
        lst[mi] *= al;
#pragma unroll
        for (int dt = 0; dt < 8; ++dt)
#pragma unroll
          for (int jr = 0; jr < 4; ++jr) o[mi][dt][jr] *= al;
      }
      float rs = 0.f;
      float p[4][4];
#pragma unroll
      for (int nt = 0; nt < 4; ++nt)
#pragma unroll
        for (int jr = 0; jr < 4; ++jr) {
          p[nt][jr] = exp2v(s[mi][nt][jr] - mst[mi]);
          rs += p[nt][jr];
        }
      rs += __shfl_xor(rs, 16);
      rs += __shfl_xor(rs, 32);
      lst[mi] += rs;
#pragma unroll
      for (int nt = 0; nt < 4; ++nt) {
        pw[mi][nt][0] = cvtpk(p[nt][0], p[nt][1]);  // keys 4g+0,4g+1 of nt
        pw[mi][nt][1] = cvtpk(p[nt][2], p[nt][3]);  // keys 4g+2,4g+3
      }
    }

    // ---- O^T += V^T @ P^T ----
    // B-frag lane (g,lq) needs P[q=lq][key = kk2*32+8g+j]: sits in lanes
    // sg0=32*(g&1)+lq (j=0..3) and sg1=sg0+16 (j=4..7), tile nt=2*kk2+(g>>1).
    const int sg0 = ((g & 1) << 5) + lq;
    const int sg1 = sg0 + 16;
    const bool hi = (g & 2) != 0;
#pragma unroll
    for (int kk2 = 0; kk2 < 2; ++kk2) {
      bf16x8 av[8];
#pragma unroll
      for (int dt = 0; dt < 8; ++dt)
        av[dt] = *(const bf16x8*)((const char*)Vs[cur] + (dt * 16 + lq) * 128 +
                                  ((kk2 * 64 + g * 16) ^ sx));
#pragma unroll
      for (int mi = 0; mi < 2; ++mi) {
        unsigned a0 = __shfl(pw[mi][2 * kk2][0], sg0);
        unsigned a1 = __shfl(pw[mi][2 * kk2 + 1][0], sg0);
        unsigned a2 = __shfl(pw[mi][2 * kk2][1], sg0);
        unsigned a3 = __shfl(pw[mi][2 * kk2 + 1][1], sg0);
        unsigned a4 = __shfl(pw[mi][2 * kk2][0], sg1);
        unsigned a5 = __shfl(pw[mi][2 * kk2 + 1][0], sg1);
        unsigned a6 = __shfl(pw[mi][2 * kk2][1], sg1);
        unsigned a7 = __shfl(pw[mi][2 * kk2 + 1][1], sg1);
        union { unsigned u[4]; bf16x8 v; } pb;
        pb.u[0] = hi ? a1 : a0;
        pb.u[1] = hi ? a3 : a2;
        pb.u[2] = hi ? a5 : a4;
        pb.u[3] = hi ? a7 : a6;
#pragma unroll
        for (int dt = 0; dt < 8; ++dt) o[mi][dt] = MFMA16(av[dt], pb.v, o[mi][dt]);
      }
    }

    __builtin_amdgcn_sched_barrier(0);
    __builtin_amdgcn_s_barrier();  // all reads of buf[cur] done before restage
  }

  // ---- epilogue: normalize, store O (transpose back: lane writes 4 d's) ----
#pragma unroll
  for (int mi = 0; mi < 2; ++mi) {
    const float inv = 1.f / lst[mi];
    const int q = qbase + w * 32 + mi * 16 + lq;
#pragma unroll
    for (int dt = 0; dt < 8; ++dt) {
      bf16x4 ov = {(bf16)(o[mi][dt][0] * inv), (bf16)(o[mi][dt][1] * inv),
                   (bf16)(o[mi][dt][2] * inv), (bf16)(o[mi][dt][3] * inv)};
      *(bf16x4*)(AO + q * 2048 + h * 128 + dt * 16 + 4 * g) = ov;
    }
  }
}

// ---------------------------------------------------------------------------
// Launch. Workspace layout (peak 54.6MB, sequential reuse):
//   [0        , 16777216) : Xb  -> reused as AO after QKV GEMM
//   [16777216 , 29360128) : WT  (Wq|Wk|Wv)^T -> reused as Wo^T
//   [29360128 , 46137344) : Qb  [4096][2048] (pre-scaled by log2e/sqrt(128))
//   [46137344 , 50331648) : Kb  [4096][512]
//   [50331648 , 54525952) : Vt  [512][4096]
// ---------------------------------------------------------------------------
extern "C" void kernel_launch(void* const* d_in, const int* in_sizes, int n_in,
                              void* d_out, int out_size, void* d_ws, size_t ws_size,
                              hipStream_t stream) {
  const float* X = (const float*)d_in[0];
  const float* Wq = (const float*)d_in[2];
  const float* Wk = (const float*)d_in[3];
  const float* Wv = (const float*)d_in[4];
  const float* Wo = (const float*)d_in[5];
  float* out = (float*)d_out;
  char* ws = (char*)d_ws;

  bf16* Xb = (bf16*)ws;
  bf16* WT = (bf16*)(ws + 16777216);
  bf16* Qb = (bf16*)(ws + 29360128);
  bf16* Kb = (bf16*)(ws + 46137344);
  bf16* Vt = (bf16*)(ws + 50331648);

  cast_bf16_kernel<<<2048, 256, 0, stream>>>(X, Xb, (4096 * 2048) / 4);
  // fold 1/sqrt(128) * log2(e) into Wq^T so softmax runs in exp2 domain
  transpose_cast_kernel<<<dim3(32, 32), 256, 0, stream>>>(
      Wq, 2048, WT, 0.08838834764831845f * 1.4426950408889634f);
  transpose_cast_kernel<<<dim3(8, 32), 256, 0, stream>>>(Wk, 512, WT + 2048 * 2048, 1.0f);
  transpose_cast_kernel<<<dim3(8, 32), 256, 0, stream>>>(Wv, 512, WT + 2560 * 2048, 1.0f);

  gemm_bt<0><<<dim3(24, 32), 256, 0, stream>>>(Xb, WT, 2048, Qb, Kb, Vt, (float*)nullptr);

  transpose_cast_kernel<<<dim3(32, 32), 256, 0, stream>>>(Wo, 2048, WT, 1.0f);

  attn_fwd<<<512, 256, 0, stream>>>(Qb, Kb, Vt, Xb);

  gemm_bt<1><<<dim3(16, 32), 256, 0, stream>>>(Xb, WT, 2048, (bf16*)nullptr,
                                               (bf16*)nullptr, (bf16*)nullptr, out);
}

// Round 4
// 263.227 us; speedup vs baseline: 1.5500x; 1.0694x over previous
//
#include <hip/hip_runtime.h>

// ---------------------------------------------------------------------------
// Fused GQA attention block for MI355X (gfx950), bf16 MFMA pipeline.
// B=1, S=4096, H=2048, NH=16, NKV=4, HD=128, GROUPS=4, causal mask hardcoded.
// Round 4: r3 (32x32x16 MFMA attention, permlane P-redistribution) with the
// reduction-swap aliasing bug fixed: cross-half max/sum now use __shfl_xor(32)
// instead of PLSWAP on two copies of the SAME SSA value (which the register
// allocator legally coalesces into one VGPR -> self-swap -> wrong reductions).
// ---------------------------------------------------------------------------

typedef __bf16 bf16;
typedef float f32x4 __attribute__((ext_vector_type(4)));
typedef float f32x16 __attribute__((ext_vector_type(16)));
typedef bf16 bf16x4 __attribute__((ext_vector_type(4)));
typedef bf16 bf16x8 __attribute__((ext_vector_type(8)));
typedef unsigned u32x4 __attribute__((ext_vector_type(4)));

#define MFMA16(A, B, C) __builtin_amdgcn_mfma_f32_16x16x32_bf16((A), (B), (C), 0, 0, 0)
#define MFMA32(A, B, C) __builtin_amdgcn_mfma_f32_32x32x16_bf16((A), (B), (C), 0, 0, 0)

__device__ __forceinline__ void async16(const bf16* g, bf16* l) {
  __builtin_amdgcn_global_load_lds(
      (const __attribute__((address_space(1))) unsigned int*)g,
      (__attribute__((address_space(3))) unsigned int*)l, 16, 0, 0);
}

__device__ __forceinline__ float exp2v(float x) {
  float r; asm("v_exp_f32 %0, %1" : "=v"(r) : "v"(x)); return r;
}
__device__ __forceinline__ unsigned cvtpk(float a, float b) {  // lo=a, hi=b
  unsigned r; asm("v_cvt_pk_bf16_f32 %0, %1, %2" : "=v"(r) : "v"(a), "v"(b)); return r;
}
// v_permlane32_swap_b32: a' = [a_lo|b_lo], b' = [a_hi|b_hi].
// ONLY safe when a and b are distinct SSA values (else RA may coalesce regs).
#define PLSWAP(a, b) asm("v_permlane32_swap_b32 %0, %1" : "+v"(a), "+v"(b))

// B-fragment builder: dwords {a0', a1', c0', c1'} after half-swaps
__device__ __forceinline__ bf16x8 mkfrag(unsigned a0, unsigned a1,
                                         unsigned c0, unsigned c1) {
  PLSWAP(a0, c0);
  PLSWAP(a1, c1);
  u32x4 t = {a0, a1, c0, c1};
  return __builtin_bit_cast(bf16x8, t);
}

// ---------------------------------------------------------------------------
// f32 -> bf16 elementwise cast
// ---------------------------------------------------------------------------
__global__ void cast_bf16_kernel(const float* __restrict__ in,
                                 bf16* __restrict__ out, int n4) {
  int i = blockIdx.x * blockDim.x + threadIdx.x;
  int stride = gridDim.x * blockDim.x;
  for (; i < n4; i += stride) {
    float4 v = ((const float4*)in)[i];
    bf16x4 o = {(bf16)v.x, (bf16)v.y, (bf16)v.z, (bf16)v.w};
    ((bf16x4*)out)[i] = o;
  }
}

// ---------------------------------------------------------------------------
// Transpose + cast: src f32 [2048][srcCols] -> dst bf16 [srcCols][2048], *scale
// ---------------------------------------------------------------------------
__global__ void transpose_cast_kernel(const float* __restrict__ src, int srcCols,
                                      bf16* __restrict__ dst, float scale) {
  __shared__ float t[64][65];
  const int kt = blockIdx.y * 64;
  const int nt = blockIdx.x * 64;
  const int r0 = threadIdx.x >> 4;
  const int c0 = (threadIdx.x & 15) * 4;
#pragma unroll
  for (int i = 0; i < 4; ++i) {
    int r = r0 + i * 16;
    float4 v = *(const float4*)(src + (kt + r) * srcCols + nt + c0);
    t[r][c0 + 0] = v.x; t[r][c0 + 1] = v.y; t[r][c0 + 2] = v.z; t[r][c0 + 3] = v.w;
  }
  __syncthreads();
#pragma unroll
  for (int i = 0; i < 4; ++i) {
    int r = r0 + i * 16;
    bf16x4 b = {(bf16)(t[c0 + 0][r] * scale), (bf16)(t[c0 + 1][r] * scale),
                (bf16)(t[c0 + 2][r] * scale), (bf16)(t[c0 + 3][r] * scale)};
    *(bf16x4*)(dst + (nt + r) * 2048 + kt + c0) = b;
  }
}

// ---------------------------------------------------------------------------
// 128x128-tile bf16 GEMM, BK=32, 4 waves, global_load_lds staging (unchanged).
// ---------------------------------------------------------------------------
template <int MODE>
__global__ __launch_bounds__(256, 2) void gemm_bt(
    const bf16* __restrict__ A, const bf16* __restrict__ BT, int K,
    bf16* __restrict__ Qb, bf16* __restrict__ Kb, bf16* __restrict__ Vt,
    float* __restrict__ Cf) {
  __shared__ bf16 As[128 * 32];
  __shared__ bf16 Bs[128 * 32];
  const int tid = threadIdx.x;
  const int w = tid >> 6, lane = tid & 63, g = lane >> 4, lq = lane & 15;
  const int wr = w >> 1, wc = w & 1;
  const int mBase = blockIdx.y * 128, nBase = blockIdx.x * 128;

  f32x4 acc[4][4] = {};
  const int KT = K >> 5;
  for (int kt = 0; kt < KT; ++kt) {
#pragma unroll
    for (int r = 0; r < 2; ++r) {
      int chunk = r * 256 + tid;
      int row = chunk >> 2, cu = chunk & 3;
      async16(A + (mBase + row) * K + kt * 32 + cu * 8, As + (r * 256 + w * 64) * 8);
      async16(BT + (nBase + row) * K + kt * 32 + cu * 8, Bs + (r * 256 + w * 64) * 8);
    }
    asm volatile("s_waitcnt vmcnt(0)" ::: "memory");
    __syncthreads();

    bf16x8 af[4], bfr[4];
#pragma unroll
    for (int i = 0; i < 4; ++i)
      af[i] = *(const bf16x8*)(As + (wr * 64 + i * 16 + lq) * 32 + g * 8);
#pragma unroll
    for (int i = 0; i < 4; ++i)
      bfr[i] = *(const bf16x8*)(Bs + (wc * 64 + i * 16 + lq) * 32 + g * 8);
#pragma unroll
    for (int mi = 0; mi < 4; ++mi)
#pragma unroll
      for (int ni = 0; ni < 4; ++ni)
        acc[mi][ni] = MFMA16(af[mi], bfr[ni], acc[mi][ni]);
    __syncthreads();
  }

#pragma unroll
  for (int mi = 0; mi < 4; ++mi)
#pragma unroll
    for (int ni = 0; ni < 4; ++ni) {
      const int n = nBase + wc * 64 + ni * 16 + lq;
      const int m0 = mBase + wr * 64 + mi * 16 + 4 * g;
      if (MODE == 0) {
        if (nBase < 2048) {
#pragma unroll
          for (int jr = 0; jr < 4; ++jr)
            Qb[(m0 + jr) * 2048 + n] = (bf16)acc[mi][ni][jr];
        } else if (nBase < 2560) {
#pragma unroll
          for (int jr = 0; jr < 4; ++jr)
            Kb[(m0 + jr) * 512 + (n - 2048)] = (bf16)acc[mi][ni][jr];
        } else {
          bf16x4 v = {(bf16)acc[mi][ni][0], (bf16)acc[mi][ni][1],
                      (bf16)acc[mi][ni][2], (bf16)acc[mi][ni][3]};
          *(bf16x4*)(Vt + (n - 2560) * 4096 + m0) = v;
        }
      } else {
#pragma unroll
        for (int jr = 0; jr < 4; ++jr)
          Cf[(m0 + jr) * 2048 + n] = acc[mi][ni][jr];
      }
    }
}

// ---------------------------------------------------------------------------
// Causal flash attention, swapped-QK^T on 32x32x16 MFMA, P in registers.
// Block = (head, 128-row q-tile), 4 waves x 32 q-rows, KVBLK=64 double-buffered.
// Q pre-scaled by log2e/sqrt(HD) (exp2 domain).
// S^T = mfma32(K, Q): lane (g2=lane>>5, l5=lane&31) holds
//   S^T[key = ts*32 + (r&3)+8*(r>>2)+4*g2][q = l5],  r = 0..15, ts = 0,1.
// PV B-frag (O^T = mfma32(V^T, P)) needs P[key=KK*16+8*g2+e][q=l5]:
//   pw[wi] = cvtpk(p[2wi], p[2wi+1]); per KK two v_permlane32_swap build it.
// ---------------------------------------------------------------------------
__global__ __launch_bounds__(256, 2) void attn_fwd(
    const bf16* __restrict__ Qb,  // [4096][2048], scale folded
    const bf16* __restrict__ Kb,  // [4096][512]
    const bf16* __restrict__ Vt,  // [512][4096]
    bf16* __restrict__ AO) {      // [4096][2048]
  // K: [buf][64 key][128 d] 256B rows; V: [buf][128 d][64 key] 128B rows.
  // Both XOR-swizzled: 16B-unit ^= (row&7), inverse applied at global source.
  __shared__ __align__(16) bf16 Ks[2][64 * 128];
  __shared__ __align__(16) bf16 Vs[2][128 * 64];

  const int bid = blockIdx.x;
  const int h = bid & 15;
  const int qt = (bid < 256) ? (bid >> 4) : (31 - ((bid - 256) >> 4));
  const int kv = h >> 2;
  const int tid = threadIdx.x;
  const int w = tid >> 6, lane = tid & 63, l5 = lane & 31, g2 = lane >> 5;
  const int sxr = (l5 & 7) << 4;
  const int qbase = qt * 128;
  const int nk = 2 * (qt + 1);
  const int qw = qbase + w * 32 + l5;  // this lane's q row

  // Q fragments (B-operand): Q[qw][d = kk*16 + 8*g2 + e]
  bf16x8 aq[8];
  {
    const bf16* qrow = Qb + qw * 2048 + h * 128;
#pragma unroll
    for (int kk = 0; kk < 8; ++kk)
      aq[kk] = *(const bf16x8*)(qrow + kk * 16 + g2 * 8);
  }

  float mst = -1e30f, lst = 0.f;
  f32x16 o[4] = {};  // O^T: o[dt][r] = O^T[d = dt*32 + crow(r,g2)][q = l5]

  auto STAGE = [&](int t) {
    const int b = t & 1;
#pragma unroll
    for (int r = 0; r < 4; ++r) {
      int gid = r * 256 + tid;
      int krow = gid >> 4, cu = gid & 15;
      async16(Kb + (t * 64 + krow) * 512 + kv * 128 + ((cu ^ (krow & 7)) * 8),
              &Ks[b][(r * 256 + w * 64) * 8]);
    }
#pragma unroll
    for (int r = 0; r < 4; ++r) {
      int gid = r * 256 + tid;
      int vrow = gid >> 3, gv = gid & 7;
      async16(Vt + (kv * 128 + vrow) * 4096 + t * 64 + ((gv ^ (vrow & 7)) * 8),
              &Vs[b][(r * 256 + w * 64) * 8]);
    }
  };

  STAGE(0);

  for (int t = 0; t < nk; ++t) {
    const int cur = t & 1;
    if (t + 1 < nk) {
      STAGE(t + 1);
      asm volatile("s_waitcnt vmcnt(8)" ::: "memory");
    } else {
      asm volatile("s_waitcnt vmcnt(0)" ::: "memory");
    }
    __builtin_amdgcn_s_barrier();
    __builtin_amdgcn_sched_barrier(0);

    // ---- S^T = K @ Q^T : two 32-key tiles ----
    f32x16 s0 = {}, s1 = {};
    {
      const char* kb0 = (const char*)&Ks[cur][0] + l5 * 256;
      __builtin_amdgcn_s_setprio(1);
#pragma unroll
      for (int kk = 0; kk < 8; ++kk) {
        const int off = (kk * 32 + g2 * 16) ^ sxr;
        bf16x8 k0 = *(const bf16x8*)(kb0 + off);
        bf16x8 k1 = *(const bf16x8*)(kb0 + 8192 + off);
        s0 = MFMA32(k0, aq[kk], s0);
        s1 = MFMA32(k1, aq[kk], s1);
      }
      __builtin_amdgcn_s_setprio(0);
    }

    // ---- causal mask (last two 64-key tiles only) ----
    if (t >= 2 * qt) {
      const int kb = t * 64 + 4 * g2;
#pragma unroll
      for (int r = 0; r < 16; ++r) {
        const int key = kb + (r & 3) + 8 * (r >> 2);
        if (key > qw) s0[r] = -1e30f;
        if (key + 32 > qw) s1[r] = -1e30f;
      }
    }

    // ---- online softmax (exp2 domain), tree reductions ----
    {
      float mx[16];
#pragma unroll
      for (int r = 0; r < 16; ++r) mx[r] = fmaxf(s0[r], s1[r]);
#pragma unroll
      for (int off = 8; off > 0; off >>= 1)
#pragma unroll
        for (int r = 0; r < off; ++r) mx[r] = fmaxf(mx[r], mx[r + off]);
      const float pm = fmaxf(mx[0], __shfl_xor(mx[0], 32));  // cross-half max

      if (__any(pm > mst + 8.f)) {  // defer-max (T13), THR=8 in log2
        const float mn = fmaxf(mst, pm);
        const float al = exp2v(mst - mn);
        mst = mn;
        lst *= al;
#pragma unroll
        for (int dt = 0; dt < 4; ++dt)
#pragma unroll
          for (int r = 0; r < 16; ++r) o[dt][r] *= al;
      }
#pragma unroll
      for (int r = 0; r < 16; ++r) {
        s0[r] = exp2v(s0[r] - mst);
        s1[r] = exp2v(s1[r] - mst);
      }
      float sm[16];
#pragma unroll
      for (int r = 0; r < 16; ++r) sm[r] = s0[r] + s1[r];
#pragma unroll
      for (int off = 8; off > 0; off >>= 1)
#pragma unroll
        for (int r = 0; r < off; ++r) sm[r] += sm[r + off];
      lst += sm[0] + __shfl_xor(sm[0], 32);  // cross-half sum
    }

    // ---- pack P to bf16 words: pw[wi] = keys (2wi, 2wi+1) of this lane ----
    unsigned pw0[8], pw1[8];
#pragma unroll
    for (int wi = 0; wi < 8; ++wi) {
      pw0[wi] = cvtpk(s0[2 * wi], s0[2 * wi + 1]);
      pw1[wi] = cvtpk(s1[2 * wi], s1[2 * wi + 1]);
    }
    // B-fragments for the 4 PV K-steps (2 permlane32_swap each)
    bf16x8 pb0 = mkfrag(pw0[0], pw0[1], pw0[2], pw0[3]);
    bf16x8 pb1 = mkfrag(pw0[4], pw0[5], pw0[6], pw0[7]);
    bf16x8 pb2 = mkfrag(pw1[0], pw1[1], pw1[2], pw1[3]);
    bf16x8 pb3 = mkfrag(pw1[4], pw1[5], pw1[6], pw1[7]);

    // ---- O^T += V^T @ P ----
    {
      __builtin_amdgcn_s_setprio(1);
#pragma unroll
      for (int dt = 0; dt < 4; ++dt) {
        const char* vb = (const char*)&Vs[cur][0] + (dt * 32 + l5) * 128;
        bf16x8 av;
        av = *(const bf16x8*)(vb + ((0 * 32 + g2 * 16) ^ sxr));
        o[dt] = MFMA32(av, pb0, o[dt]);
        av = *(const bf16x8*)(vb + ((1 * 32 + g2 * 16) ^ sxr));
        o[dt] = MFMA32(av, pb1, o[dt]);
        av = *(const bf16x8*)(vb + ((2 * 32 + g2 * 16) ^ sxr));
        o[dt] = MFMA32(av, pb2, o[dt]);
        av = *(const bf16x8*)(vb + ((3 * 32 + g2 * 16) ^ sxr));
        o[dt] = MFMA32(av, pb3, o[dt]);
      }
      __builtin_amdgcn_s_setprio(0);
    }

    __builtin_amdgcn_sched_barrier(0);
    __builtin_amdgcn_s_barrier();  // all reads of buf[cur] done before restage
  }

  // ---- epilogue: normalize, store (4 consecutive d per reg quad) ----
  {
    const float inv = 1.f / lst;
    bf16* aob = AO + qw * 2048 + h * 128;
#pragma unroll
    for (int dt = 0; dt < 4; ++dt)
#pragma unroll
      for (int m = 0; m < 4; ++m) {
        bf16x4 ov = {(bf16)(o[dt][4 * m + 0] * inv), (bf16)(o[dt][4 * m + 1] * inv),
                     (bf16)(o[dt][4 * m + 2] * inv), (bf16)(o[dt][4 * m + 3] * inv)};
        *(bf16x4*)(aob + dt * 32 + 8 * m + 4 * g2) = ov;
      }
  }
}

// ---------------------------------------------------------------------------
// Launch. Workspace layout (peak 54.6MB, sequential reuse):
//   [0        , 16777216) : Xb  -> reused as AO after QKV GEMM
//   [16777216 , 29360128) : WT  (Wq|Wk|Wv)^T -> reused as Wo^T
//   [29360128 , 46137344) : Qb  [4096][2048] (pre-scaled by log2e/sqrt(128))
//   [46137344 , 50331648) : Kb  [4096][512]
//   [50331648 , 54525952) : Vt  [512][4096]
// ---------------------------------------------------------------------------
extern "C" void kernel_launch(void* const* d_in, const int* in_sizes, int n_in,
                              void* d_out, int out_size, void* d_ws, size_t ws_size,
                              hipStream_t stream) {
  const float* X = (const float*)d_in[0];
  const float* Wq = (const float*)d_in[2];
  const float* Wk = (const float*)d_in[3];
  const float* Wv = (const float*)d_in[4];
  const float* Wo = (const float*)d_in[5];
  float* out = (float*)d_out;
  char* ws = (char*)d_ws;

  bf16* Xb = (bf16*)ws;
  bf16* WT = (bf16*)(ws + 16777216);
  bf16* Qb = (bf16*)(ws + 29360128);
  bf16* Kb = (bf16*)(ws + 46137344);
  bf16* Vt = (bf16*)(ws + 50331648);

  cast_bf16_kernel<<<2048, 256, 0, stream>>>(X, Xb, (4096 * 2048) / 4);
  transpose_cast_kernel<<<dim3(32, 32), 256, 0, stream>>>(
      Wq, 2048, WT, 0.08838834764831845f * 1.4426950408889634f);
  transpose_cast_kernel<<<dim3(8, 32), 256, 0, stream>>>(Wk, 512, WT + 2048 * 2048, 1.0f);
  transpose_cast_kernel<<<dim3(8, 32), 256, 0, stream>>>(Wv, 512, WT + 2560 * 2048, 1.0f);

  gemm_bt<0><<<dim3(24, 32), 256, 0, stream>>>(Xb, WT, 2048, Qb, Kb, Vt, (float*)nullptr);

  transpose_cast_kernel<<<dim3(32, 32), 256, 0, stream>>>(Wo, 2048, WT, 1.0f);

  attn_fwd<<<512, 256, 0, stream>>>(Qb, Kb, Vt, Xb);

  gemm_bt<1><<<dim3(16, 32), 256, 0, stream>>>(Xb, WT, 2048, (bf16*)nullptr,
                                               (bf16*)nullptr, (bf16*)nullptr, out);
}

// Round 5
// 258.026 us; speedup vs baseline: 1.5812x; 1.0202x over previous
//
#include <hip/hip_runtime.h>

// ---------------------------------------------------------------------------
// Fused GQA attention block for MI355X (gfx950), bf16 MFMA pipeline.
// B=1, S=4096, H=2048, NH=16, NKV=4, HD=128, GROUPS=4, causal mask hardcoded.
// Round 5: attention software-pipelined: per iter, softmax(t) runs BEFORE the
// MFMA cluster [QK(t+1) || PV(t)] (interleaved 1:1), so softmax is off the
// QK->PV critical path and the cluster has 6 independent MFMA dep-chains.
// K staged 2 tiles ahead, V 1 ahead; uniform vmcnt(8) counted waits.
// ---------------------------------------------------------------------------

typedef __bf16 bf16;
typedef float f32x4 __attribute__((ext_vector_type(4)));
typedef float f32x16 __attribute__((ext_vector_type(16)));
typedef bf16 bf16x4 __attribute__((ext_vector_type(4)));
typedef bf16 bf16x8 __attribute__((ext_vector_type(8)));
typedef unsigned u32x4 __attribute__((ext_vector_type(4)));

#define MFMA16(A, B, C) __builtin_amdgcn_mfma_f32_16x16x32_bf16((A), (B), (C), 0, 0, 0)
#define MFMA32(A, B, C) __builtin_amdgcn_mfma_f32_32x32x16_bf16((A), (B), (C), 0, 0, 0)

__device__ __forceinline__ void async16(const bf16* g, bf16* l) {
  __builtin_amdgcn_global_load_lds(
      (const __attribute__((address_space(1))) unsigned int*)g,
      (__attribute__((address_space(3))) unsigned int*)l, 16, 0, 0);
}

__device__ __forceinline__ float exp2v(float x) {
  float r; asm("v_exp_f32 %0, %1" : "=v"(r) : "v"(x)); return r;
}
__device__ __forceinline__ unsigned cvtpk(float a, float b) {  // lo=a, hi=b
  unsigned r; asm("v_cvt_pk_bf16_f32 %0, %1, %2" : "=v"(r) : "v"(a), "v"(b)); return r;
}
// v_permlane32_swap_b32: a' = [a_lo|b_lo], b' = [a_hi|b_hi].
// ONLY safe when a and b are distinct SSA values (else RA may coalesce regs).
#define PLSWAP(a, b) asm("v_permlane32_swap_b32 %0, %1" : "+v"(a), "+v"(b))

// B-fragment builder: dwords {a0', a1', c0', c1'} after half-swaps
__device__ __forceinline__ bf16x8 mkfrag(unsigned a0, unsigned a1,
                                         unsigned c0, unsigned c1) {
  PLSWAP(a0, c0);
  PLSWAP(a1, c1);
  u32x4 t = {a0, a1, c0, c1};
  return __builtin_bit_cast(bf16x8, t);
}

// ---------------------------------------------------------------------------
// f32 -> bf16 elementwise cast
// ---------------------------------------------------------------------------
__global__ void cast_bf16_kernel(const float* __restrict__ in,
                                 bf16* __restrict__ out, int n4) {
  int i = blockIdx.x * blockDim.x + threadIdx.x;
  int stride = gridDim.x * blockDim.x;
  for (; i < n4; i += stride) {
    float4 v = ((const float4*)in)[i];
    bf16x4 o = {(bf16)v.x, (bf16)v.y, (bf16)v.z, (bf16)v.w};
    ((bf16x4*)out)[i] = o;
  }
}

// ---------------------------------------------------------------------------
// Transpose + cast: src f32 [2048][srcCols] -> dst bf16 [srcCols][2048], *scale
// ---------------------------------------------------------------------------
__global__ void transpose_cast_kernel(const float* __restrict__ src, int srcCols,
                                      bf16* __restrict__ dst, float scale) {
  __shared__ float t[64][65];
  const int kt = blockIdx.y * 64;
  const int nt = blockIdx.x * 64;
  const int r0 = threadIdx.x >> 4;
  const int c0 = (threadIdx.x & 15) * 4;
#pragma unroll
  for (int i = 0; i < 4; ++i) {
    int r = r0 + i * 16;
    float4 v = *(const float4*)(src + (kt + r) * srcCols + nt + c0);
    t[r][c0 + 0] = v.x; t[r][c0 + 1] = v.y; t[r][c0 + 2] = v.z; t[r][c0 + 3] = v.w;
  }
  __syncthreads();
#pragma unroll
  for (int i = 0; i < 4; ++i) {
    int r = r0 + i * 16;
    bf16x4 b = {(bf16)(t[c0 + 0][r] * scale), (bf16)(t[c0 + 1][r] * scale),
                (bf16)(t[c0 + 2][r] * scale), (bf16)(t[c0 + 3][r] * scale)};
    *(bf16x4*)(dst + (nt + r) * 2048 + kt + c0) = b;
  }
}

// ---------------------------------------------------------------------------
// 128x128-tile bf16 GEMM, BK=32, 4 waves, global_load_lds staging (unchanged).
// ---------------------------------------------------------------------------
template <int MODE>
__global__ __launch_bounds__(256, 2) void gemm_bt(
    const bf16* __restrict__ A, const bf16* __restrict__ BT, int K,
    bf16* __restrict__ Qb, bf16* __restrict__ Kb, bf16* __restrict__ Vt,
    float* __restrict__ Cf) {
  __shared__ bf16 As[128 * 32];
  __shared__ bf16 Bs[128 * 32];
  const int tid = threadIdx.x;
  const int w = tid >> 6, lane = tid & 63, g = lane >> 4, lq = lane & 15;
  const int wr = w >> 1, wc = w & 1;
  const int mBase = blockIdx.y * 128, nBase = blockIdx.x * 128;

  f32x4 acc[4][4] = {};
  const int KT = K >> 5;
  for (int kt = 0; kt < KT; ++kt) {
#pragma unroll
    for (int r = 0; r < 2; ++r) {
      int chunk = r * 256 + tid;
      int row = chunk >> 2, cu = chunk & 3;
      async16(A + (mBase + row) * K + kt * 32 + cu * 8, As + (r * 256 + w * 64) * 8);
      async16(BT + (nBase + row) * K + kt * 32 + cu * 8, Bs + (r * 256 + w * 64) * 8);
    }
    asm volatile("s_waitcnt vmcnt(0)" ::: "memory");
    __syncthreads();

    bf16x8 af[4], bfr[4];
#pragma unroll
    for (int i = 0; i < 4; ++i)
      af[i] = *(const bf16x8*)(As + (wr * 64 + i * 16 + lq) * 32 + g * 8);
#pragma unroll
    for (int i = 0; i < 4; ++i)
      bfr[i] = *(const bf16x8*)(Bs + (wc * 64 + i * 16 + lq) * 32 + g * 8);
#pragma unroll
    for (int mi = 0; mi < 4; ++mi)
#pragma unroll
      for (int ni = 0; ni < 4; ++ni)
        acc[mi][ni] = MFMA16(af[mi], bfr[ni], acc[mi][ni]);
    __syncthreads();
  }

#pragma unroll
  for (int mi = 0; mi < 4; ++mi)
#pragma unroll
    for (int ni = 0; ni < 4; ++ni) {
      const int n = nBase + wc * 64 + ni * 16 + lq;
      const int m0 = mBase + wr * 64 + mi * 16 + 4 * g;
      if (MODE == 0) {
        if (nBase < 2048) {
#pragma unroll
          for (int jr = 0; jr < 4; ++jr)
            Qb[(m0 + jr) * 2048 + n] = (bf16)acc[mi][ni][jr];
        } else if (nBase < 2560) {
#pragma unroll
          for (int jr = 0; jr < 4; ++jr)
            Kb[(m0 + jr) * 512 + (n - 2048)] = (bf16)acc[mi][ni][jr];
        } else {
          bf16x4 v = {(bf16)acc[mi][ni][0], (bf16)acc[mi][ni][1],
                      (bf16)acc[mi][ni][2], (bf16)acc[mi][ni][3]};
          *(bf16x4*)(Vt + (n - 2560) * 4096 + m0) = v;
        }
      } else {
#pragma unroll
        for (int jr = 0; jr < 4; ++jr)
          Cf[(m0 + jr) * 2048 + n] = acc[mi][ni][jr];
      }
    }
}

// ---------------------------------------------------------------------------
// Causal flash attention, swapped-QK^T on 32x32x16 MFMA, P in registers,
// software-pipelined (QK one tile ahead of softmax/PV).
//
// Per iter t: softmax(t) on s(t); STAGE K(t+2)->Ks[t&1], V(t+1)->Vs[(t+1)&1];
// vmcnt(8) (retires K(t+1),V(t), leaves 8 in flight); barrier;
// cluster: QK(t+1) from Ks[(t+1)&1] interleaved with PV(t) from Vs[t&1];
// barrier. Prologue computes QK(0) standalone.
// ---------------------------------------------------------------------------
__global__ __launch_bounds__(256, 2) void attn_fwd(
    const bf16* __restrict__ Qb,  // [4096][2048], scale folded
    const bf16* __restrict__ Kb,  // [4096][512]
    const bf16* __restrict__ Vt,  // [512][4096]
    bf16* __restrict__ AO) {      // [4096][2048]
  // K: [buf][64 key][128 d] 256B rows; V: [buf][128 d][64 key] 128B rows.
  // Both XOR-swizzled: 16B-unit ^= (row&7), inverse applied at global source.
  __shared__ __align__(16) bf16 Ks[2][64 * 128];
  __shared__ __align__(16) bf16 Vs[2][128 * 64];

  const int bid = blockIdx.x;
  const int h = bid & 15;
  const int qt = (bid < 256) ? (bid >> 4) : (31 - ((bid - 256) >> 4));
  const int kv = h >> 2;
  const int tid = threadIdx.x;
  const int w = tid >> 6, lane = tid & 63, l5 = lane & 31, g2 = lane >> 5;
  const int sxr = (l5 & 7) << 4;
  const int qbase = qt * 128;
  const int nk = 2 * (qt + 1);
  const int qw = qbase + w * 32 + l5;  // this lane's q row

  // Q fragments (B-operand): Q[qw][d = kk*16 + 8*g2 + e]
  bf16x8 aq[8];
  {
    const bf16* qrow = Qb + qw * 2048 + h * 128;
#pragma unroll
    for (int kk = 0; kk < 8; ++kk)
      aq[kk] = *(const bf16x8*)(qrow + kk * 16 + g2 * 8);
  }

  float mst = -1e30f, lst = 0.f;
  f32x16 o[4] = {};  // O^T: o[dt][r] = O^T[d = dt*32 + crow(r,g2)][q = l5]

  auto STAGE_K = [&](int t, int buf) {
#pragma unroll
    for (int r = 0; r < 4; ++r) {
      int gid = r * 256 + tid;
      int krow = gid >> 4, cu = gid & 15;
      async16(Kb + (t * 64 + krow) * 512 + kv * 128 + ((cu ^ (krow & 7)) * 8),
              &Ks[buf][(r * 256 + w * 64) * 8]);
    }
  };
  auto STAGE_V = [&](int t, int buf) {
#pragma unroll
    for (int r = 0; r < 4; ++r) {
      int gid = r * 256 + tid;
      int vrow = gid >> 3, gv = gid & 7;
      async16(Vt + (kv * 128 + vrow) * 4096 + t * 64 + ((gv ^ (vrow & 7)) * 8),
              &Vs[buf][(r * 256 + w * 64) * 8]);
    }
  };

  // ---- prologue: K(0), V(0), K(1) in flight; compute QK(0) ----
  STAGE_K(0, 0);
  STAGE_V(0, 0);
  STAGE_K(1, 1);
  asm volatile("s_waitcnt vmcnt(8)" ::: "memory");  // K(0) done
  __builtin_amdgcn_s_barrier();
  __builtin_amdgcn_sched_barrier(0);

  f32x16 s0 = {}, s1 = {};
  {
    const char* kb0 = (const char*)&Ks[0][0] + l5 * 256;
    __builtin_amdgcn_s_setprio(1);
#pragma unroll
    for (int kk = 0; kk < 8; ++kk) {
      const int off = (kk * 32 + g2 * 16) ^ sxr;
      bf16x8 k0 = *(const bf16x8*)(kb0 + off);
      bf16x8 k1 = *(const bf16x8*)(kb0 + 8192 + off);
      s0 = MFMA32(k0, aq[kk], s0);
      s1 = MFMA32(k1, aq[kk], s1);
    }
    __builtin_amdgcn_s_setprio(0);
  }
  __builtin_amdgcn_sched_barrier(0);
  __builtin_amdgcn_s_barrier();  // QK(0) reads done before K(2)->Ks[0]

  for (int t = 0; t < nk; ++t) {
    const int cur = t & 1, nxt = (t + 1) & 1;

    // ---- causal mask on s(t) (last two 64-key tiles only) ----
    if (t >= 2 * qt) {
      const int kb = t * 64 + 4 * g2;
#pragma unroll
      for (int r = 0; r < 16; ++r) {
        const int key = kb + (r & 3) + 8 * (r >> 2);
        if (key > qw) s0[r] = -1e30f;
        if (key + 32 > qw) s1[r] = -1e30f;
      }
    }

    // ---- online softmax(t) (exp2 domain), tree reductions ----
    {
      float mx[16];
#pragma unroll
      for (int r = 0; r < 16; ++r) mx[r] = fmaxf(s0[r], s1[r]);
#pragma unroll
      for (int off = 8; off > 0; off >>= 1)
#pragma unroll
        for (int r = 0; r < off; ++r) mx[r] = fmaxf(mx[r], mx[r + off]);
      const float pm = fmaxf(mx[0], __shfl_xor(mx[0], 32));  // cross-half max

      if (__any(pm > mst + 8.f)) {  // defer-max (T13), THR=8 in log2
        const float mn = fmaxf(mst, pm);
        const float al = exp2v(mst - mn);
        mst = mn;
        lst *= al;
#pragma unroll
        for (int dt = 0; dt < 4; ++dt)
#pragma unroll
          for (int r = 0; r < 16; ++r) o[dt][r] *= al;
      }
#pragma unroll
      for (int r = 0; r < 16; ++r) {
        s0[r] = exp2v(s0[r] - mst);
        s1[r] = exp2v(s1[r] - mst);
      }
      float sm[16];
#pragma unroll
      for (int r = 0; r < 16; ++r) sm[r] = s0[r] + s1[r];
#pragma unroll
      for (int off = 8; off > 0; off >>= 1)
#pragma unroll
        for (int r = 0; r < off; ++r) sm[r] += sm[r + off];
      lst += sm[0] + __shfl_xor(sm[0], 32);  // cross-half sum
    }

    // ---- pack P(t) to bf16 B-fragments (cvt_pk + permlane32_swap) ----
    bf16x8 pb[4];
    {
      unsigned pw0[8], pw1[8];
#pragma unroll
      for (int wi = 0; wi < 8; ++wi) {
        pw0[wi] = cvtpk(s0[2 * wi], s0[2 * wi + 1]);
        pw1[wi] = cvtpk(s1[2 * wi], s1[2 * wi + 1]);
      }
      pb[0] = mkfrag(pw0[0], pw0[1], pw0[2], pw0[3]);
      pb[1] = mkfrag(pw0[4], pw0[5], pw0[6], pw0[7]);
      pb[2] = mkfrag(pw1[0], pw1[1], pw1[2], pw1[3]);
      pb[3] = mkfrag(pw1[4], pw1[5], pw1[6], pw1[7]);
    }

    // ---- stage K(t+2) -> Ks[cur], V(t+1) -> Vs[nxt] (clamped at tail) ----
    STAGE_K(min(t + 2, nk - 1), cur);
    STAGE_V(min(t + 1, nk - 1), nxt);
    // retires K(t+1), V(t); leaves the 8 just-issued loads in flight
    asm volatile("s_waitcnt vmcnt(8)" ::: "memory");
    __builtin_amdgcn_s_barrier();
    __builtin_amdgcn_sched_barrier(0);

    // ---- MFMA cluster: QK(t+1) || PV(t), interleaved 1:1 ----
    f32x16 n0 = {}, n1 = {};
    const char* kb0 = (const char*)&Ks[nxt][0] + l5 * 256;
    const char* vb0 = (const char*)&Vs[cur][0];
    if (t + 1 < nk) {
      __builtin_amdgcn_s_setprio(1);
#pragma unroll
      for (int i = 0; i < 8; ++i) {
        const int koff = (i * 32 + g2 * 16) ^ sxr;
        bf16x8 k0 = *(const bf16x8*)(kb0 + koff);
        bf16x8 k1 = *(const bf16x8*)(kb0 + 8192 + koff);
        n0 = MFMA32(k0, aq[i], n0);
        n1 = MFMA32(k1, aq[i], n1);
        // PV steps j = 2i, 2i+1: dt = j&3, KK = j>>2
        {
          const int j = 2 * i, dt = j & 3, KK = j >> 2;
          bf16x8 av = *(const bf16x8*)(vb0 + (dt * 32 + l5) * 128 +
                                       ((KK * 32 + g2 * 16) ^ sxr));
          o[dt] = MFMA32(av, pb[KK], o[dt]);
        }
        {
          const int j = 2 * i + 1, dt = j & 3, KK = j >> 2;
          bf16x8 av = *(const bf16x8*)(vb0 + (dt * 32 + l5) * 128 +
                                       ((KK * 32 + g2 * 16) ^ sxr));
          o[dt] = MFMA32(av, pb[KK], o[dt]);
        }
      }
      __builtin_amdgcn_s_setprio(0);
    } else {
      // tail: PV(t) only
      __builtin_amdgcn_s_setprio(1);
#pragma unroll
      for (int j = 0; j < 16; ++j) {
        const int dt = j & 3, KK = j >> 2;
        bf16x8 av = *(const bf16x8*)(vb0 + (dt * 32 + l5) * 128 +
                                     ((KK * 32 + g2 * 16) ^ sxr));
        o[dt] = MFMA32(av, pb[KK], o[dt]);
      }
      __builtin_amdgcn_s_setprio(0);
    }
    __builtin_amdgcn_sched_barrier(0);
    __builtin_amdgcn_s_barrier();  // cluster reads done before next restage

    s0 = n0;
    s1 = n1;
  }

  // ---- epilogue: normalize, store (4 consecutive d per reg quad) ----
  {
    const float inv = 1.f / lst;
    bf16* aob = AO + qw * 2048 + h * 128;
#pragma unroll
    for (int dt = 0; dt < 4; ++dt)
#pragma unroll
      for (int m = 0; m < 4; ++m) {
        bf16x4 ov = {(bf16)(o[dt][4 * m + 0] * inv), (bf16)(o[dt][4 * m + 1] * inv),
                     (bf16)(o[dt][4 * m + 2] * inv), (bf16)(o[dt][4 * m + 3] * inv)};
        *(bf16x4*)(aob + dt * 32 + 8 * m + 4 * g2) = ov;
      }
  }
}

// ---------------------------------------------------------------------------
// Launch. Workspace layout (peak 54.6MB, sequential reuse):
//   [0        , 16777216) : Xb  -> reused as AO after QKV GEMM
//   [16777216 , 29360128) : WT  (Wq|Wk|Wv)^T -> reused as Wo^T
//   [29360128 , 46137344) : Qb  [4096][2048] (pre-scaled by log2e/sqrt(128))
//   [46137344 , 50331648) : Kb  [4096][512]
//   [50331648 , 54525952) : Vt  [512][4096]
// ---------------------------------------------------------------------------
extern "C" void kernel_launch(void* const* d_in, const int* in_sizes, int n_in,
                              void* d_out, int out_size, void* d_ws, size_t ws_size,
                              hipStream_t stream) {
  const float* X = (const float*)d_in[0];
  const float* Wq = (const float*)d_in[2];
  const float* Wk = (const float*)d_in[3];
  const float* Wv = (const float*)d_in[4];
  const float* Wo = (const float*)d_in[5];
  float* out = (float*)d_out;
  char* ws = (char*)d_ws;

  bf16* Xb = (bf16*)ws;
  bf16* WT = (bf16*)(ws + 16777216);
  bf16* Qb = (bf16*)(ws + 29360128);
  bf16* Kb = (bf16*)(ws + 46137344);
  bf16* Vt = (bf16*)(ws + 50331648);

  cast_bf16_kernel<<<2048, 256, 0, stream>>>(X, Xb, (4096 * 2048) / 4);
  transpose_cast_kernel<<<dim3(32, 32), 256, 0, stream>>>(
      Wq, 2048, WT, 0.08838834764831845f * 1.4426950408889634f);
  transpose_cast_kernel<<<dim3(8, 32), 256, 0, stream>>>(Wk, 512, WT + 2048 * 2048, 1.0f);
  transpose_cast_kernel<<<dim3(8, 32), 256, 0, stream>>>(Wv, 512, WT + 2560 * 2048, 1.0f);

  gemm_bt<0><<<dim3(24, 32), 256, 0, stream>>>(Xb, WT, 2048, Qb, Kb, Vt, (float*)nullptr);

  transpose_cast_kernel<<<dim3(32, 32), 256, 0, stream>>>(Wo, 2048, WT, 1.0f);

  attn_fwd<<<512, 256, 0, stream>>>(Qb, Kb, Vt, Xb);

  gemm_bt<1><<<dim3(16, 32), 256, 0, stream>>>(Xb, WT, 2048, (bf16*)nullptr,
                                               (bf16*)nullptr, (bf16*)nullptr, out);
}